// Round 1
// baseline (933.164 us; speedup 1.0000x reference)
//
#include <hip/hip_runtime.h>
#include <math.h>

#define DIM 256
#define TILE 64
#define BK 16

// ---------------------------------------------------------------------------
// Kernel 1: squared row norms of cond (c2) and sol (s2).
// One wave (64 lanes) per row; each lane loads one float4 (64*4 = 256 = DIM).
// ---------------------------------------------------------------------------
__global__ void norms_kernel(const float* __restrict__ C,
                             const float* __restrict__ S,
                             float* __restrict__ c2,
                             float* __restrict__ s2, int N) {
    int gtid = blockIdx.x * blockDim.x + threadIdx.x;
    int wave = gtid >> 6;
    int lane = gtid & 63;
    if (wave >= 2 * N) return;
    const float* base = (wave < N) ? (C + (size_t)wave * DIM)
                                   : (S + (size_t)(wave - N) * DIM);
    float4 v = ((const float4*)base)[lane];
    float sum = v.x * v.x + v.y * v.y + v.z * v.z + v.w * v.w;
    #pragma unroll
    for (int off = 32; off > 0; off >>= 1)
        sum += __shfl_down(sum, off, 64);
    if (lane == 0) {
        if (wave < N) c2[wave] = sum;
        else          s2[wave - N] = sum;
    }
}

// ---------------------------------------------------------------------------
// Kernel 2: tiled "GEMM" over the pairwise matrix with fused epilogue.
// Each 256-thread block computes a 64x64 tile of dot products (4x4 per
// thread), converts to exp(-dist*scale), accumulates row/col partial sums in
// LDS, then one global atomicAdd per row/col. Diagonal sim captured directly.
// sim <= 0 and sim >= about -45 here, so exp() never under/overflows fp32 and
// no max-subtraction pass is needed for logsumexp.
// ---------------------------------------------------------------------------
__global__ __launch_bounds__(256) void tile_kernel(
        const float* __restrict__ C, const float* __restrict__ S,
        const float* __restrict__ c2, const float* __restrict__ s2,
        const float* __restrict__ temp,
        float* __restrict__ rowsum, float* __restrict__ colsum,
        float* __restrict__ diag, int N) {
    __shared__ float As[BK][TILE + 1];   // As[k][m] = C[bm+m][k0+k]
    __shared__ float Bs[BK][TILE + 1];   // Bs[k][n] = S[bn+n][k0+k]
    __shared__ float rs[TILE], cs[TILE];

    const int bm = blockIdx.y * TILE;
    const int bn = blockIdx.x * TILE;
    const int tid = threadIdx.x;
    const int tx = tid & 15;   // column group (4 cols)
    const int ty = tid >> 4;   // row group (4 rows)

    float acc[4][4] = {};

    for (int k0 = 0; k0 < DIM; k0 += BK) {
        // Stage: 64 rows x 16 k-cols for each matrix; 256 threads each load
        // one float4 along k and store transposed into LDS.
        int r  = tid >> 2;          // 0..63: row within tile
        int kq = (tid & 3) * 4;     // 0,4,8,12
        float4 a = *(const float4*)(C + (size_t)(bm + r) * DIM + k0 + kq);
        float4 b = *(const float4*)(S + (size_t)(bn + r) * DIM + k0 + kq);
        As[kq + 0][r] = a.x; As[kq + 1][r] = a.y;
        As[kq + 2][r] = a.z; As[kq + 3][r] = a.w;
        Bs[kq + 0][r] = b.x; Bs[kq + 1][r] = b.y;
        Bs[kq + 2][r] = b.z; Bs[kq + 3][r] = b.w;
        __syncthreads();

        #pragma unroll
        for (int k = 0; k < BK; ++k) {
            float av[4], bv[4];
            #pragma unroll
            for (int i = 0; i < 4; ++i) av[i] = As[k][ty * 4 + i];
            #pragma unroll
            for (int j = 0; j < 4; ++j) bv[j] = Bs[k][tx * 4 + j];
            #pragma unroll
            for (int i = 0; i < 4; ++i)
                #pragma unroll
                for (int j = 0; j < 4; ++j)
                    acc[i][j] = fmaf(av[i], bv[j], acc[i][j]);
        }
        __syncthreads();
    }

    // Epilogue
    if (tid < TILE) { rs[tid] = 0.0f; cs[tid] = 0.0f; }
    __syncthreads();

    const float scale = expf(temp[0]);
    float rpart[4] = {0.f, 0.f, 0.f, 0.f};
    float cpart[4] = {0.f, 0.f, 0.f, 0.f};

    #pragma unroll
    for (int i = 0; i < 4; ++i) {
        const int grow = bm + ty * 4 + i;
        const float c2v = c2[grow];
        #pragma unroll
        for (int j = 0; j < 4; ++j) {
            const int gcol = bn + tx * 4 + j;
            float d2 = c2v + s2[gcol] - 2.0f * acc[i][j];
            d2 = fmaxf(d2, 0.0f);
            float sim = -sqrtf(d2) * scale;
            float e = expf(sim);
            rpart[i] += e;
            cpart[j] += e;
            if (grow == gcol) diag[grow] = sim;
        }
    }
    #pragma unroll
    for (int i = 0; i < 4; ++i) atomicAdd(&rs[ty * 4 + i], rpart[i]);
    #pragma unroll
    for (int j = 0; j < 4; ++j) atomicAdd(&cs[tx * 4 + j], cpart[j]);
    __syncthreads();

    if (tid < TILE) {
        atomicAdd(&rowsum[bm + tid], rs[tid]);
        atomicAdd(&colsum[bn + tid], cs[tid]);
    }
}

// ---------------------------------------------------------------------------
// Kernel 3: finalize. loss = (1/2N) * sum_i [log(rowsum_i) - diag_i
//                                          + log(colsum_i) - diag_i]
// ---------------------------------------------------------------------------
__global__ void finalize_kernel(const float* __restrict__ rowsum,
                                const float* __restrict__ colsum,
                                const float* __restrict__ diag,
                                float* __restrict__ out, int N) {
    __shared__ float red[256];
    float sum = 0.0f;
    for (int i = threadIdx.x; i < N; i += 256) {
        sum += (logf(rowsum[i]) - diag[i]) + (logf(colsum[i]) - diag[i]);
    }
    red[threadIdx.x] = sum;
    __syncthreads();
    for (int s = 128; s > 0; s >>= 1) {
        if (threadIdx.x < s) red[threadIdx.x] += red[threadIdx.x + s];
        __syncthreads();
    }
    if (threadIdx.x == 0) out[0] = red[0] / (2.0f * (float)N);
}

extern "C" void kernel_launch(void* const* d_in, const int* in_sizes, int n_in,
                              void* d_out, int out_size, void* d_ws, size_t ws_size,
                              hipStream_t stream) {
    const float* C = (const float*)d_in[0];
    const float* S = (const float*)d_in[1];
    const float* T = (const float*)d_in[2];
    const int N = in_sizes[0] / DIM;   // 8192

    float* ws     = (float*)d_ws;
    float* c2     = ws;
    float* s2     = ws + N;
    float* rowsum = ws + 2 * N;
    float* colsum = ws + 3 * N;
    float* diag   = ws + 4 * N;

    // rowsum+colsum are contiguous: one async memset (graph-capture safe)
    hipMemsetAsync(rowsum, 0, (size_t)2 * N * sizeof(float), stream);

    {
        int waves = 2 * N;
        int threads = waves * 64;
        norms_kernel<<<(threads + 255) / 256, 256, 0, stream>>>(C, S, c2, s2, N);
    }
    {
        dim3 grid(N / TILE, N / TILE);
        tile_kernel<<<grid, 256, 0, stream>>>(C, S, c2, s2, T, rowsum, colsum, diag, N);
    }
    finalize_kernel<<<1, 256, 0, stream>>>(rowsum, colsum, diag, (float*)d_out, N);
}

// Round 2
// 161.680 us; speedup vs baseline: 5.7717x; 5.7717x over previous
//
#include <hip/hip_runtime.h>
#include <math.h>

#define DIM 256
#define TM 128
#define TN 128
#define BK 32

typedef __bf16 bf16x8 __attribute__((ext_vector_type(8)));
typedef float f32x4 __attribute__((ext_vector_type(4)));

typedef const __attribute__((address_space(1))) void* gas_ptr;
typedef __attribute__((address_space(3))) void* las_ptr;

__device__ __forceinline__ void async_cp16(const void* g, void* l) {
    __builtin_amdgcn_global_load_lds((gas_ptr)g, (las_ptr)l, 16, 0, 0);
}

__device__ __forceinline__ unsigned short f32_to_bf16(float f) {
    unsigned int u = __float_as_uint(f);
    u += 0x7FFFu + ((u >> 16) & 1u);   // round-to-nearest-even (inputs are finite normals)
    return (unsigned short)(u >> 16);
}

// ---------------------------------------------------------------------------
// Kernel 1: fp32 -> bf16 conversion (for MFMA) + exact fp32 row norms.
// One wave per row; lane loads float4 (64*4 = 256 = DIM).
// ---------------------------------------------------------------------------
__global__ __launch_bounds__(256) void convert_kernel(
        const float* __restrict__ C, const float* __restrict__ S,
        unsigned short* __restrict__ Cb, unsigned short* __restrict__ Sb,
        float* __restrict__ c2, float* __restrict__ s2, int N) {
    int gtid = blockIdx.x * 256 + threadIdx.x;
    int row = gtid >> 6;
    int lane = gtid & 63;
    if (row >= 2 * N) return;
    const float* src;
    unsigned short* dst;
    if (row < N) { src = C + (size_t)row * DIM; dst = Cb + (size_t)row * DIM; }
    else         { src = S + (size_t)(row - N) * DIM; dst = Sb + (size_t)(row - N) * DIM; }
    float4 v = ((const float4*)src)[lane];
    ushort4 b;
    b.x = f32_to_bf16(v.x); b.y = f32_to_bf16(v.y);
    b.z = f32_to_bf16(v.z); b.w = f32_to_bf16(v.w);
    ((ushort4*)dst)[lane] = b;
    float nrm = v.x * v.x + v.y * v.y + v.z * v.z + v.w * v.w;
    #pragma unroll
    for (int off = 32; off > 0; off >>= 1) nrm += __shfl_down(nrm, off, 64);
    if (lane == 0) { if (row < N) c2[row] = nrm; else s2[row - N] = nrm; }
}

// ---------------------------------------------------------------------------
// Kernel 2: bf16 MFMA GEMM (m97 structure) with fused contrastive epilogue.
// 128x128 tile, 256 threads = 4 waves in 2x2; each wave: 4x4 frags of
// 16x16x32 MFMA. Staging via global_load_lds width=16 into XOR-swizzled LDS
// (chunk ^= (row>>2)&3 -> 2-way b128 conflicts, which are free).
// Epilogue: e = exp(-sqrt(max(c2+s2-2dot,0)) * e^T); row/col sums via
// in-register shuffle reduce -> LDS -> 1 global atomic per row/col per block.
// sim in [-50, 0] so exp never under/overflows fp32: single-pass logsumexp.
// ---------------------------------------------------------------------------
__global__ __launch_bounds__(256) void mfma_kernel(
        const unsigned short* __restrict__ Cb, const unsigned short* __restrict__ Sb,
        const float* __restrict__ c2, const float* __restrict__ s2,
        const float* __restrict__ temp,
        float* __restrict__ rowsum, float* __restrict__ colsum,
        float* __restrict__ diag, int N) {
    __shared__ __align__(16) unsigned short Abuf[TM * BK];   // 8 KB, swizzled [row][chunk]
    __shared__ __align__(16) unsigned short Bbuf[TN * BK];   // 8 KB
    __shared__ float rs[TM], cs[TN], c2t[TM], s2t[TN];

    const int tid = threadIdx.x;
    const int bm = blockIdx.y * TM;
    const int bn = blockIdx.x * TN;
    const int w  = tid >> 6;
    const int l  = tid & 63;
    const int wm = (w >> 1) * 64;   // wave row offset in tile
    const int wn = (w & 1) * 64;    // wave col offset in tile

    if (tid < TM) { rs[tid] = 0.0f; c2t[tid] = c2[bm + tid]; }
    else          { int t = tid - TM; cs[t] = 0.0f; s2t[t] = s2[bn + t]; }

    // --- staging addresses (lane l handles LDS slot l*16B of its region) ---
    // slot l <-> (row = region_base + l/4, chunk c = l&3); source chunk is
    // swizzled: data at slot (r,c) = global chunk c ^ ((r>>2)&3).
    const int rstage = w * 16 + (l >> 2);                  // 0..63
    const int kqs = (l & 3) ^ ((rstage >> 2) & 3);
    const unsigned short* gA = Cb + (size_t)(bm + rstage) * DIM + kqs * 8;
    const unsigned short* gB = Sb + (size_t)(bn + rstage) * DIM + kqs * 8;
    unsigned short* lA0 = &Abuf[w * 512];
    unsigned short* lA1 = &Abuf[(w + 4) * 512];
    unsigned short* lB0 = &Bbuf[w * 512];
    unsigned short* lB1 = &Bbuf[(w + 4) * 512];
    const size_t rowskip = (size_t)64 * DIM;               // rows +64: same swizzle

    // --- fragment LDS offsets (ushort indices); layout A[m=l&15][k=q*8+j] ---
    const int m16 = l & 15;
    const int q = l >> 4;
    int aoff[4], boff[4];
    #pragma unroll
    for (int i = 0; i < 4; ++i) {
        int rA = wm + i * 16 + m16;
        aoff[i] = rA * BK + (q ^ ((rA >> 2) & 3)) * 8;
        int rB = wn + i * 16 + m16;
        boff[i] = rB * BK + (q ^ ((rB >> 2) & 3)) * 8;
    }

    f32x4 acc[4][4] = {};

    for (int k0 = 0; k0 < DIM; k0 += BK) {
        async_cp16(gA, lA0);
        async_cp16(gA + rowskip, lA1);
        async_cp16(gB, lB0);
        async_cp16(gB + rowskip, lB1);
        gA += BK; gB += BK;
        __syncthreads();   // waits vmcnt(0): staging complete

        bf16x8 af[4], bf[4];
        #pragma unroll
        for (int i = 0; i < 4; ++i) af[i] = *(const bf16x8*)&Abuf[aoff[i]];
        #pragma unroll
        for (int i = 0; i < 4; ++i) bf[i] = *(const bf16x8*)&Bbuf[boff[i]];
        #pragma unroll
        for (int mi = 0; mi < 4; ++mi)
            #pragma unroll
            for (int ni = 0; ni < 4; ++ni)
                acc[mi][ni] = __builtin_amdgcn_mfma_f32_16x16x32_bf16(
                    af[mi], bf[ni], acc[mi][ni], 0, 0, 0);
        __syncthreads();   // LDS consumed; safe to overwrite next iter
    }

    // --- fused epilogue ---
    // C/D layout (m89-verified): col = lane&15, row = (lane>>4)*4 + reg.
    const float escale = __expf(temp[0]);
    const bool diagblk = (bm == bn);

    float rpart[4][4];   // [mi][reg]
    #pragma unroll
    for (int mi = 0; mi < 4; ++mi)
        #pragma unroll
        for (int r = 0; r < 4; ++r) rpart[mi][r] = 0.0f;
    float cpart[4] = {0.f, 0.f, 0.f, 0.f};

    #pragma unroll
    for (int mi = 0; mi < 4; ++mi) {
        #pragma unroll
        for (int ni = 0; ni < 4; ++ni) {
            #pragma unroll
            for (int r = 0; r < 4; ++r) {
                int ri = wm + mi * 16 + q * 4 + r;   // row in tile
                int ci = wn + ni * 16 + m16;         // col in tile
                float d2 = c2t[ri] + s2t[ci] - 2.0f * acc[mi][ni][r];
                d2 = fmaxf(d2, 0.0f);
                float dist = d2 * __frsqrt_rn(fmaxf(d2, 1e-20f));
                float sim = -dist * escale;
                float e = __expf(sim);
                rpart[mi][r] += e;
                cpart[ni] += e;
                if (diagblk && ri == ci) diag[bm + ri] = sim;
            }
        }
    }
    // reduce row partials across the 16 lanes sharing q (masks stay in-quad)
    #pragma unroll
    for (int mask = 1; mask < 16; mask <<= 1)
        #pragma unroll
        for (int mi = 0; mi < 4; ++mi)
            #pragma unroll
            for (int r = 0; r < 4; ++r)
                rpart[mi][r] += __shfl_xor(rpart[mi][r], mask, 64);
    if (m16 == 0) {
        #pragma unroll
        for (int mi = 0; mi < 4; ++mi)
            #pragma unroll
            for (int r = 0; r < 4; ++r)
                atomicAdd(&rs[wm + mi * 16 + q * 4 + r], rpart[mi][r]);
    }
    // reduce col partials across the 4 quads
    #pragma unroll
    for (int mask = 16; mask < 64; mask <<= 1)
        #pragma unroll
        for (int ni = 0; ni < 4; ++ni)
            cpart[ni] += __shfl_xor(cpart[ni], mask, 64);
    if (q == 0) {
        #pragma unroll
        for (int ni = 0; ni < 4; ++ni)
            atomicAdd(&cs[wn + ni * 16 + m16], cpart[ni]);
    }
    __syncthreads();
    if (tid < TM) atomicAdd(&rowsum[bm + tid], rs[tid]);
    else          atomicAdd(&colsum[bn + tid - TM], cs[tid - TM]);
}

// ---------------------------------------------------------------------------
// Kernel 3: finalize. loss = (1/2N) * sum_i [log(rowsum_i)+log(colsum_i)-2*diag_i]
// ---------------------------------------------------------------------------
__global__ void finalize_kernel(const float* __restrict__ rowsum,
                                const float* __restrict__ colsum,
                                const float* __restrict__ diag,
                                float* __restrict__ out, int N) {
    __shared__ float red[256];
    float sum = 0.0f;
    for (int i = threadIdx.x; i < N; i += 256)
        sum += logf(rowsum[i]) + logf(colsum[i]) - 2.0f * diag[i];
    red[threadIdx.x] = sum;
    __syncthreads();
    for (int s = 128; s > 0; s >>= 1) {
        if (threadIdx.x < s) red[threadIdx.x] += red[threadIdx.x + s];
        __syncthreads();
    }
    if (threadIdx.x == 0) out[0] = red[0] / (2.0f * (float)N);
}

extern "C" void kernel_launch(void* const* d_in, const int* in_sizes, int n_in,
                              void* d_out, int out_size, void* d_ws, size_t ws_size,
                              hipStream_t stream) {
    const float* C = (const float*)d_in[0];
    const float* S = (const float*)d_in[1];
    const float* T = (const float*)d_in[2];
    const int N = in_sizes[0] / DIM;   // 8192

    float* ws     = (float*)d_ws;
    float* c2     = ws;
    float* s2     = ws + N;
    float* rowsum = ws + 2 * N;
    float* colsum = ws + 3 * N;
    float* diag   = ws + 4 * N;
    unsigned short* Cb = (unsigned short*)(ws + 5 * N);   // 5N*4 bytes: 16B-aligned
    unsigned short* Sb = Cb + (size_t)N * DIM;

    hipMemsetAsync(rowsum, 0, (size_t)2 * N * sizeof(float), stream);

    convert_kernel<<<(2 * N * 64) / 256, 256, 0, stream>>>(C, S, Cb, Sb, c2, s2, N);

    dim3 grid(N / TN, N / TM);
    mfma_kernel<<<grid, 256, 0, stream>>>(Cb, Sb, c2, s2, T, rowsum, colsum, diag, N);

    finalize_kernel<<<1, 256, 0, stream>>>(rowsum, colsum, diag, (float*)d_out, N);
}

// Round 3
// 139.211 us; speedup vs baseline: 6.7032x; 1.1614x over previous
//
#include <hip/hip_runtime.h>
#include <math.h>

#define DIM 256
#define TM 128
#define TN 128
#define BK 64

typedef __bf16 bf16x8 __attribute__((ext_vector_type(8)));
typedef float f32x4 __attribute__((ext_vector_type(4)));

typedef const __attribute__((address_space(1))) void* gas_ptr;
typedef __attribute__((address_space(3))) void* las_ptr;

__device__ __forceinline__ void async_cp16(const void* g, void* l) {
    __builtin_amdgcn_global_load_lds((gas_ptr)g, (las_ptr)l, 16, 0, 0);
}

__device__ __forceinline__ unsigned short f32_to_bf16(float f) {
    unsigned int u = __float_as_uint(f);
    u += 0x7FFFu + ((u >> 16) & 1u);   // RNE; inputs are finite normals
    return (unsigned short)(u >> 16);
}

// ---------------------------------------------------------------------------
// Kernel 1: fp32 -> bf16 convert + exact fp32 row norms + zero-init of the
// rowsum/colsum accumulators and out[0] (replaces the hipMemsetAsync node).
// One wave per row; lane loads one float4 (64*4 = 256 = DIM).
// ---------------------------------------------------------------------------
__global__ __launch_bounds__(256) void convert_kernel(
        const float* __restrict__ C, const float* __restrict__ S,
        unsigned short* __restrict__ Cb, unsigned short* __restrict__ Sb,
        float* __restrict__ c2, float* __restrict__ s2,
        float* __restrict__ sums0,   // rowsum..colsum, 2N floats contiguous
        float* __restrict__ out, int N) {
    int gtid = blockIdx.x * 256 + threadIdx.x;
    if (gtid < 2 * N) sums0[gtid] = 0.0f;
    if (gtid == 0) out[0] = 0.0f;
    int row = gtid >> 6;
    int lane = gtid & 63;
    if (row >= 2 * N) return;
    const float* src;
    unsigned short* dst;
    if (row < N) { src = C + (size_t)row * DIM; dst = Cb + (size_t)row * DIM; }
    else         { src = S + (size_t)(row - N) * DIM; dst = Sb + (size_t)(row - N) * DIM; }
    float4 v = ((const float4*)src)[lane];
    ushort4 b;
    b.x = f32_to_bf16(v.x); b.y = f32_to_bf16(v.y);
    b.z = f32_to_bf16(v.z); b.w = f32_to_bf16(v.w);
    ((ushort4*)dst)[lane] = b;
    float nrm = v.x * v.x + v.y * v.y + v.z * v.z + v.w * v.w;
    #pragma unroll
    for (int off = 32; off > 0; off >>= 1) nrm += __shfl_down(nrm, off, 64);
    if (lane == 0) { if (row < N) c2[row] = nrm; else s2[row - N] = nrm; }
}

// ---------------------------------------------------------------------------
// Kernel 2: bf16 MFMA GEMM, 128x128 tile, BK=64 (4 K-iters, half the barrier
// drains of BK=32; 8 cp16/lane in flight per drain). LDS layout: row-major
// 128 rows x 8 chunks of 16B, physical chunk = logical ^ (row&7) so both the
// wave-uniform global_load_lds staging and the ds_read_b128 fragment reads
// are conflict-free. Fused epilogue: e = exp(-dist*e^T), row/col sums via
// shuffle reduce -> LDS -> 1 global atomic per row/col. diag stores DIST
// (finalize applies -2*e^T*dist). sim in [-50,0]: no exp range issues.
// ---------------------------------------------------------------------------
__global__ __launch_bounds__(256) void mfma_kernel(
        const unsigned short* __restrict__ Cb, const unsigned short* __restrict__ Sb,
        const float* __restrict__ c2, const float* __restrict__ s2,
        const float* __restrict__ temp,
        float* __restrict__ rowsum, float* __restrict__ colsum,
        float* __restrict__ diag, int N) {
    __shared__ __align__(16) unsigned short Abuf[TM * BK];   // 16 KB
    __shared__ __align__(16) unsigned short Bbuf[TN * BK];   // 16 KB
    __shared__ float rs[TM], cs[TN], c2t[TM], s2t[TN];

    const int tid = threadIdx.x;
    const int bm = blockIdx.y * TM;
    const int bn = blockIdx.x * TN;
    const int w  = tid >> 6;
    const int l  = tid & 63;
    const int wm = (w >> 1) * 64;
    const int wn = (w & 1) * 64;

    if (tid < TM) { rs[tid] = 0.0f; c2t[tid] = c2[bm + tid]; }
    else          { int t = tid - TM; cs[t] = 0.0f; s2t[t] = s2[bn + t]; }

    // --- staging: slot s = i*256 + w*64 + l  <->  (row = s>>3, pchunk = s&7)
    // data for (row, pchunk) = global chunk pchunk ^ (row&7); row&7 == l>>3.
    const int l8 = l >> 3, l7 = l & 7;
    const int gch = l7 ^ l8;
    const unsigned short* gAl = Cb + (size_t)(bm + w * 8 + l8) * DIM + gch * 8;
    const unsigned short* gBl = Sb + (size_t)(bn + w * 8 + l8) * DIM + gch * 8;
    unsigned short* lA = &Abuf[w * 512];      // wave-uniform base, +i*2048/instr
    unsigned short* lB = &Bbuf[w * 512];
    const size_t istep = (size_t)32 * DIM;    // +32 rows per staging instr

    // --- fragment offsets: A[m = l&15][k = q*8+j], q = l>>4.
    // row*64 + ((4t+q)^(row&7))*8 ; (4t+q)^x == (q^x)^(4t) since q<4.
    const int m16 = l & 15;
    const int q = l >> 4;
    const int m7 = m16 & 7;
    int aoff[4], boff[4];
    #pragma unroll
    for (int i = 0; i < 4; ++i) {
        aoff[i] = (wm + i * 16 + m16) * BK + (q ^ m7) * 8;
        boff[i] = (wn + i * 16 + m16) * BK + (q ^ m7) * 8;
    }

    f32x4 acc[4][4] = {};

    #pragma unroll
    for (int kk = 0; kk < 4; ++kk) {
        #pragma unroll
        for (int i = 0; i < 4; ++i) {
            async_cp16(gAl + i * istep, lA + i * 2048);
            async_cp16(gBl + i * istep, lB + i * 2048);
        }
        gAl += BK; gBl += BK;
        __syncthreads();   // staging complete (vmcnt drain)

        #pragma unroll
        for (int t = 0; t < 2; ++t) {
            bf16x8 af[4], bf[4];
            #pragma unroll
            for (int i = 0; i < 4; ++i) af[i] = *(const bf16x8*)&Abuf[aoff[i] ^ (t << 5)];
            #pragma unroll
            for (int i = 0; i < 4; ++i) bf[i] = *(const bf16x8*)&Bbuf[boff[i] ^ (t << 5)];
            #pragma unroll
            for (int mi = 0; mi < 4; ++mi)
                #pragma unroll
                for (int ni = 0; ni < 4; ++ni)
                    acc[mi][ni] = __builtin_amdgcn_mfma_f32_16x16x32_bf16(
                        af[mi], bf[ni], acc[mi][ni], 0, 0, 0);
        }
        __syncthreads();   // LDS consumed
    }

    // --- fused epilogue; C/D layout (m89): col = lane&15, row = q*4 + reg.
    const float escale = __expf(temp[0]);
    const bool diagblk = (bm == bn);

    float c2v[4][4], s2v[4];
    #pragma unroll
    for (int mi = 0; mi < 4; ++mi)
        #pragma unroll
        for (int r = 0; r < 4; ++r) c2v[mi][r] = c2t[wm + mi * 16 + q * 4 + r];
    #pragma unroll
    for (int ni = 0; ni < 4; ++ni) s2v[ni] = s2t[wn + ni * 16 + m16];

    float rpart[4][4];
    #pragma unroll
    for (int mi = 0; mi < 4; ++mi)
        #pragma unroll
        for (int r = 0; r < 4; ++r) rpart[mi][r] = 0.0f;
    float cpart[4] = {0.f, 0.f, 0.f, 0.f};

    #pragma unroll
    for (int mi = 0; mi < 4; ++mi) {
        #pragma unroll
        for (int ni = 0; ni < 4; ++ni) {
            #pragma unroll
            for (int r = 0; r < 4; ++r) {
                float d2 = fmaf(-2.0f, acc[mi][ni][r], c2v[mi][r] + s2v[ni]);
                d2 = fmaxf(d2, 0.0f);
                float dist = __builtin_amdgcn_sqrtf(d2);
                float e = __expf(-escale * dist);
                rpart[mi][r] += e;
                cpart[ni] += e;
                if (diagblk) {
                    int ri = wm + mi * 16 + q * 4 + r;
                    int ci = wn + ni * 16 + m16;
                    if (ri == ci) diag[bm + ri] = dist;
                }
            }
        }
    }
    // rows: reduce across the 16 lanes sharing q
    #pragma unroll
    for (int mask = 1; mask < 16; mask <<= 1)
        #pragma unroll
        for (int mi = 0; mi < 4; ++mi)
            #pragma unroll
            for (int r = 0; r < 4; ++r)
                rpart[mi][r] += __shfl_xor(rpart[mi][r], mask, 64);
    if (m16 == 0) {
        #pragma unroll
        for (int mi = 0; mi < 4; ++mi)
            #pragma unroll
            for (int r = 0; r < 4; ++r)
                atomicAdd(&rs[wm + mi * 16 + q * 4 + r], rpart[mi][r]);
    }
    // cols: reduce across the 4 quads
    #pragma unroll
    for (int mask = 16; mask < 64; mask <<= 1)
        #pragma unroll
        for (int ni = 0; ni < 4; ++ni)
            cpart[ni] += __shfl_xor(cpart[ni], mask, 64);
    if (q == 0) {
        #pragma unroll
        for (int ni = 0; ni < 4; ++ni)
            atomicAdd(&cs[wn + ni * 16 + m16], cpart[ni]);
    }
    __syncthreads();
    if (tid < TM) atomicAdd(&rowsum[bm + tid], rs[tid]);
    else          atomicAdd(&colsum[bn + tid - TM], cs[tid - TM]);
}

// ---------------------------------------------------------------------------
// Kernel 3: finalize (32 blocks, atomic into pre-zeroed out[0]).
// loss = (1/2N) * sum_i [log(rowsum_i) + log(colsum_i) + 2*e^T*dist_i]
// ---------------------------------------------------------------------------
__global__ __launch_bounds__(256) void finalize_kernel(
        const float* __restrict__ rowsum, const float* __restrict__ colsum,
        const float* __restrict__ diag, const float* __restrict__ temp,
        float* __restrict__ out, int N) {
    __shared__ float red[256];
    const float escale = __expf(temp[0]);
    int i = blockIdx.x * 256 + threadIdx.x;
    float v = 0.0f;
    if (i < N)
        v = __logf(rowsum[i]) + __logf(colsum[i]) + 2.0f * escale * diag[i];
    red[threadIdx.x] = v;
    __syncthreads();
    for (int s = 128; s > 0; s >>= 1) {
        if (threadIdx.x < s) red[threadIdx.x] += red[threadIdx.x + s];
        __syncthreads();
    }
    if (threadIdx.x == 0) atomicAdd(out, red[0] / (2.0f * (float)N));
}

extern "C" void kernel_launch(void* const* d_in, const int* in_sizes, int n_in,
                              void* d_out, int out_size, void* d_ws, size_t ws_size,
                              hipStream_t stream) {
    const float* C = (const float*)d_in[0];
    const float* S = (const float*)d_in[1];
    const float* T = (const float*)d_in[2];
    const int N = in_sizes[0] / DIM;   // 8192

    float* ws     = (float*)d_ws;
    float* c2     = ws;
    float* s2     = ws + N;
    float* rowsum = ws + 2 * N;
    float* colsum = ws + 3 * N;
    float* diag   = ws + 4 * N;
    unsigned short* Cb = (unsigned short*)(ws + 5 * N);   // 16B-aligned
    unsigned short* Sb = Cb + (size_t)N * DIM;

    convert_kernel<<<(2 * N * 64) / 256, 256, 0, stream>>>(
        C, S, Cb, Sb, c2, s2, rowsum, (float*)d_out, N);

    dim3 grid(N / TN, N / TM);
    mfma_kernel<<<grid, 256, 0, stream>>>(Cb, Sb, c2, s2, T, rowsum, colsum, diag, N);

    finalize_kernel<<<(N + 255) / 256, 256, 0, stream>>>(
        rowsum, colsum, diag, T, (float*)d_out, N);
}